// Round 5
// baseline (315.859 us; speedup 1.0000x reference)
//
#include <hip/hip_runtime.h>
#include <hip/hip_cooperative_groups.h>

namespace cg = cooperative_groups;

// CSATransformer: B=8, L=4096, DX=DQ=128, all f32.
// Math: (1) batch-constant softmax-logit term cancels -> dropped.
// (2) pairwise exp(sigmoid) separated via deg-6 Maclaurin + binomial moment
// sums: both O(L^2) passes -> O(L). (3) FFN as bf16 MFMA.
// ONE cooperative launch, 512 blocks x 256. Each block owns 64 rows for the
// whole kernel (rowdots -> softmax -> moments -> colsum -> FFN+LN); the only
// cross-block traffic is 111 atomic scalars + 3 grid.sync()s + Wt bf16 pack.

#define SEQ 4096
#define NB 8
#define DXC 128
#define SQRTE 1.6487212707001282f
#define Y1S 136  // LDS row stride (bf16): 68 dwords -> 2-way banks (free)

typedef __attribute__((ext_vector_type(8))) short short8;
typedef __attribute__((ext_vector_type(4))) float f32x4;

__device__ __forceinline__ float wave_sum(float v) {
#pragma unroll
  for (int m = 32; m >= 1; m >>= 1) v += __shfl_xor(v, m);
  return v;
}

__device__ __forceinline__ float qwave_sum(float v) {
#pragma unroll
  for (int m = 8; m >= 1; m >>= 1) v += __shfl_xor(v, m);
  return v;
}

__device__ __forceinline__ unsigned short f2bf(float f) {
  unsigned int u = __float_as_uint(f);
  unsigned int r = (u + 0x7FFFu + ((u >> 16) & 1u)) >> 16;
  return (unsigned short)r;
}

__device__ __forceinline__ float dot128(const float* __restrict__ a,
                                        const float* __restrict__ b) {
  const float4* A = (const float4*)a;
  const float4* B = (const float4*)b;
  float s = 0.f;
#pragma unroll 8
  for (int i = 0; i < 32; ++i) {
    float4 u = A[i], v = B[i];
    s += u.x * v.x + u.y * v.y + u.z * v.z + u.w * v.w;
  }
  return s;
}

// Maclaurin coefficients of exp(sigmoid(t))/sqrt(e)
__device__ __forceinline__ void get_ck(float* ck) {
  ck[0] = 1.0f;
  ck[1] = 0.25f;
  ck[2] = 0.03125f;
  ck[3] = -7.0f / 384.0f;
  ck[4] = -31.0f / 6144.0f;
  ck[5] = 177.0f / 122880.0f;
  ck[6] = 2017.0f / 2949120.0f;
}

__device__ __forceinline__ float binomf(int k, int m) {
  const float B[7][7] = {
      {1, 0, 0, 0, 0, 0, 0},  {1, 1, 0, 0, 0, 0, 0},   {1, 2, 1, 0, 0, 0, 0},
      {1, 3, 3, 1, 0, 0, 0},  {1, 4, 6, 4, 1, 0, 0},   {1, 5, 10, 10, 5, 1, 0},
      {1, 6, 15, 20, 15, 6, 1}};
  return B[k][m];
}

// compute coeffs C_m = SQRTE * sum_n ck[m+n]*C(m+n,m)*V[n] for m=0..6
__device__ __forceinline__ void sep_coeffs(const float* V, float* C) {
  float ck[7];
  get_ck(ck);
#pragma unroll
  for (int m = 0; m < 7; ++m) {
    float acc = 0.f;
    for (int n = 0; n <= 6 - m; ++n) acc += ck[m + n] * binomf(m + n, m) * V[n];
    C[m] = SQRTE * acc;
  }
}

__device__ __forceinline__ float horner7(const float* C, float a) {
  return (((((C[6] * a + C[5]) * a + C[4]) * a + C[3]) * a + C[2]) * a + C[1])
             * a + C[0];
}

__device__ __forceinline__ float g_exact(float t) {
  float sg = 1.0f / (1.0f + __expf(-t));
  return __expf(sg);
}

// acc layout in ws: [0..7]=ssum per batch; [8+b*6+n]=R_{n+1}; [64+b*8+n]=T_n
__global__ __launch_bounds__(256) void mega(
    const float* __restrict__ x, const float* __restrict__ W1,
    const float* __restrict__ Wsa1, const float* __restrict__ Wsa2,
    const float* __restrict__ wt_w, const float* __restrict__ wsat_w,
    const float* __restrict__ wsat_b, const float* __restrict__ bsa1,
    const float* __restrict__ pw1, const float* __restrict__ pw2,
    const float* __restrict__ b1, const float* __restrict__ b2,
    const float* __restrict__ lng, const float* __restrict__ lnb,
    float* __restrict__ acc, unsigned short* __restrict__ Wt1,
    unsigned short* __restrict__ Wt2, float* __restrict__ out) {
  cg::grid_group grid = cg::this_grid();
  __shared__ float vs[3 * DXC];
  __shared__ float t0s[64], t1s[64], t2s[64];
  __shared__ float es[64], bvs[64], dcs[64], cs[64];
  __shared__ float ccst_s;
  __shared__ __align__(16) unsigned short y1[64 * Y1S];  // 17.4 KB

  int tid = threadIdx.x;
  int blk = blockIdx.x;
  int base = blk * 64;
  int b = blk >> 6;  // 64 blocks per batch

  // ---- phase A0: per-block GEMVs v1/u1/u2 (L2-hot, redundant) + ccst
  {
    int d = tid & 127;
    if (tid < 128) {
      vs[d] = dot128(W1 + d * DXC, wt_w);
      vs[2 * DXC + d] = dot128(Wsa2 + d * DXC, wsat_w);
    } else {
      vs[DXC + d] = dot128(Wsa1 + d * DXC, wsat_w);
      if (d == 0) ccst_s = dot128(bsa1, wsat_w) + wsat_b[0];
    }
  }
  // ---- phase A1: Wt bf16 transpose-pack (blocks 0..127, 256 elems each)
  if (blk < 128) {
    int e0 = blk * 256 + tid;          // 0..32767
    int which = e0 >> 14;              // 0: pw1, 1: pw2
    int k = e0 & 16383;
    int eo = k >> 7, dd = k & 127;
    const float* pw = which ? pw2 : pw1;
    unsigned short* Wt = which ? Wt2 : Wt1;
    Wt[eo * DXC + dd] = f2bf(pw[dd * DXC + eo]);
  }
  // zero atomic accumulators (block 0) before first grid sync
  if (blk == 0 && tid < 128) acc[tid] = 0.f;
  __syncthreads();

  // ---- phase A2: rowdots for own 64 rows (quarter-wave per row, coalesced)
  int lane = tid & 63, wave = tid >> 6;
  int seg = lane & 15, sub = lane >> 4;
  {
    float4 v00 = *(const float4*)&vs[0 * DXC + seg * 8];
    float4 v01 = *(const float4*)&vs[0 * DXC + seg * 8 + 4];
    float4 v10 = *(const float4*)&vs[1 * DXC + seg * 8];
    float4 v11 = *(const float4*)&vs[1 * DXC + seg * 8 + 4];
    float4 v20 = *(const float4*)&vs[2 * DXC + seg * 8];
    float4 v21 = *(const float4*)&vs[2 * DXC + seg * 8 + 4];
    const float* xb = x + (size_t)base * DXC;
#pragma unroll
    for (int p = 0; p < 4; ++p) {
      int rl = wave * 16 + p * 4 + sub;
      const float4* xp = (const float4*)(xb + (size_t)rl * DXC + seg * 8);
      float4 lo = xp[0], hi = xp[1];
      float s0 = lo.x * v00.x + lo.y * v00.y + lo.z * v00.z + lo.w * v00.w
               + hi.x * v01.x + hi.y * v01.y + hi.z * v01.z + hi.w * v01.w;
      float s1 = lo.x * v10.x + lo.y * v10.y + lo.z * v10.z + lo.w * v10.w
               + hi.x * v11.x + hi.y * v11.y + hi.z * v11.z + hi.w * v11.w;
      float s2 = lo.x * v20.x + lo.y * v20.y + lo.z * v20.z + lo.w * v20.w
               + hi.x * v21.x + hi.y * v21.y + hi.z * v21.z + hi.w * v21.w;
      s0 = qwave_sum(s0);
      s1 = qwave_sum(s1);
      s2 = qwave_sum(s2);
      if (seg == 0) { t0s[rl] = s0; t1s[rl] = s1; t2s[rl] = s2; }
    }
  }
  __syncthreads();
  grid.sync();

  // ---- phase B: partial ssum + raw b-moments R_n = sum (e*t2)^n (wave 0)
  if (tid < 64) {
    float e = __expf(t0s[tid]);  // logits ~N(0,1): no max-sub needed
    es[tid] = e;
    float w = e * t2s[tid];
    float r[7];
    r[0] = e;
    r[1] = w;
#pragma unroll
    for (int n = 2; n < 7; ++n) r[n] = r[n - 1] * w;
#pragma unroll
    for (int n = 0; n < 7; ++n) r[n] = wave_sum(r[n]);
    if (tid == 0) {
      atomicAdd(&acc[b], r[0]);
#pragma unroll
      for (int n = 1; n < 7; ++n) atomicAdd(&acc[8 + b * 6 + n - 1], r[n]);
    }
  }
  grid.sync();

  // ---- phase C: P coeffs; per-row a,b,Z,dcol; partial T moments (wave 0)
  if (tid < 64) {
    float invS = 1.0f / acc[b];
    float Sv[7], P[7];
    Sv[0] = (float)SEQ;
    float ip = invS;
#pragma unroll
    for (int n = 1; n < 7; ++n) { Sv[n] = acc[8 + b * 6 + n - 1] * ip; ip *= invS; }
    sep_coeffs(Sv, P);
    float pp = es[tid] * invS;
    float a = pp * t1s[tid] + ccst_s;
    float bb = pp * t2s[tid];
    bvs[tid] = bb;
    float zf = horner7(P, a);
    float d = g_exact(a + bb);
    float iz = 1.0f / (zf - d);
    dcs[tid] = d * iz;
    float t[7];
    t[0] = iz;
#pragma unroll
    for (int n = 1; n < 7; ++n) t[n] = t[n - 1] * a;
#pragma unroll
    for (int n = 0; n < 7; ++n) t[n] = wave_sum(t[n]);
    if (tid == 0) {
#pragma unroll
      for (int n = 0; n < 7; ++n) atomicAdd(&acc[64 + b * 8 + n], t[n]);
    }
  }
  grid.sync();

  // ---- phase D: Q coeffs -> colsum for own rows
  if (tid < 64) {
    float Tv[7], Q[7];
#pragma unroll
    for (int n = 0; n < 7; ++n) Tv[n] = acc[64 + b * 8 + n];
    sep_coeffs(Tv, Q);
    cs[tid] = horner7(Q, bvs[tid]) - dcs[tid];
  }
  __syncthreads();

  // ---- phase E: FFN via bf16 MFMA + f32 residual + LayerNorm
  int n16 = lane & 15, quad = lane >> 4;
  int m0 = wave * 16;
  int rowA = base + m0 + n16;
  float csA = cs[m0 + n16];
  const float4* xr = (const float4*)(x + (size_t)rowA * DXC);
  short8 afr[4];
#pragma unroll
  for (int cc = 0; cc < 4; ++cc) {
    float4 p0 = xr[cc * 8 + quad * 2];
    float4 p1 = xr[cc * 8 + quad * 2 + 1];
    short8 af;
    af[0] = (short)f2bf(p0.x * csA); af[1] = (short)f2bf(p0.y * csA);
    af[2] = (short)f2bf(p0.z * csA); af[3] = (short)f2bf(p0.w * csA);
    af[4] = (short)f2bf(p1.x * csA); af[5] = (short)f2bf(p1.y * csA);
    af[6] = (short)f2bf(p1.z * csA); af[7] = (short)f2bf(p1.w * csA);
    afr[cc] = af;
  }
  // GEMM1: y1 = relu(ui @ W1p + b1) -> LDS row-major bf16
#pragma unroll
  for (int nt = 0; nt < 8; ++nt) {
    const unsigned short* wrow = Wt1 + (nt * 16 + n16) * DXC;
    f32x4 a = {0.f, 0.f, 0.f, 0.f};
#pragma unroll
    for (int cc = 0; cc < 4; ++cc) {
      short8 bf = *(const short8*)(wrow + cc * 32 + quad * 8);
      a = __builtin_amdgcn_mfma_f32_16x16x32_bf16(afr[cc], bf, a, 0, 0, 0);
    }
    float b1v = b1[nt * 16 + n16];
#pragma unroll
    for (int r = 0; r < 4; ++r) {
      float yv = fmaxf(a[r] + b1v, 0.f);
      y1[(m0 + quad * 4 + r) * Y1S + nt * 16 + n16] = f2bf(yv);
    }
  }
  __syncthreads();
  // GEMM2 A fragments from LDS (own m-tile rows)
  const unsigned short* yrow = &y1[(m0 + n16) * Y1S];
  short8 afr2[4];
#pragma unroll
  for (int cc = 0; cc < 4; ++cc)
    afr2[cc] = *(const short8*)(yrow + cc * 32 + quad * 8);
  f32x4 acc2[8];
#pragma unroll
  for (int nt = 0; nt < 8; ++nt) {
    const unsigned short* wrow = Wt2 + (nt * 16 + n16) * DXC;
    f32x4 a = {0.f, 0.f, 0.f, 0.f};
#pragma unroll
    for (int cc = 0; cc < 4; ++cc) {
      short8 bf = *(const short8*)(wrow + cc * 32 + quad * 8);
      a = __builtin_amdgcn_mfma_f32_16x16x32_bf16(afr2[cc], bf, a, 0, 0, 0);
    }
    acc2[nt] = a;
  }
  // epilogue: + b2 + f32 residual, LayerNorm per row, store
  float b2v[8], lgv[8], lbv[8];
#pragma unroll
  for (int nt = 0; nt < 8; ++nt) {
    int col = nt * 16 + n16;
    b2v[nt] = b2[col]; lgv[nt] = lng[col]; lbv[nt] = lnb[col];
  }
#pragma unroll
  for (int r = 0; r < 4; ++r) {
    int rl = m0 + quad * 4 + r;
    int row = base + rl;
    float csr = cs[rl];
    const float* xrow = x + (size_t)row * DXC;
    float z[8];
    float s = 0.f, sq = 0.f;
#pragma unroll
    for (int nt = 0; nt < 8; ++nt) {
      int col = nt * 16 + n16;
      float zz = acc2[nt][r] + b2v[nt] + xrow[col] * csr;
      z[nt] = zz; s += zz; sq += zz * zz;
    }
#pragma unroll
    for (int mm = 8; mm >= 1; mm >>= 1) {
      s += __shfl_xor(s, mm);
      sq += __shfl_xor(sq, mm);
    }
    float mu = s * 0.0078125f;
    float var = sq * 0.0078125f - mu * mu;
    float rstd = 1.0f / sqrtf(var + 1e-6f);
    float* orow = out + (size_t)row * DXC;
#pragma unroll
    for (int nt = 0; nt < 8; ++nt) {
      int col = nt * 16 + n16;
      orow[col] = (z[nt] - mu) * rstd * lgv[nt] + lbv[nt];
    }
  }
}

extern "C" void kernel_launch(void* const* d_in, const int* in_sizes, int n_in,
                              void* d_out, int out_size, void* d_ws, size_t ws_size,
                              hipStream_t stream) {
  const float* x = (const float*)d_in[0];
  const float* W1 = (const float*)d_in[2];
  const float* wt_w = (const float*)d_in[4];
  const float* Wsa1 = (const float*)d_in[6];
  const float* Wsa2 = (const float*)d_in[7];
  const float* wsat_w = (const float*)d_in[8];
  const float* wsat_b = (const float*)d_in[9];
  const float* bsa1 = (const float*)d_in[10];
  const float* pw1 = (const float*)d_in[11];
  const float* pb1 = (const float*)d_in[12];
  const float* pw2 = (const float*)d_in[13];
  const float* pb2 = (const float*)d_in[14];
  const float* lng = (const float*)d_in[15];
  const float* lnb = (const float*)d_in[16];
  float* out = (float*)d_out;
  float* ws = (float*)d_ws;

  float* acc = ws;  // 128 floats: atomic accumulators
  unsigned short* Wt1 = (unsigned short*)(ws + 128);  // 16384 ushort
  unsigned short* Wt2 = Wt1 + DXC * DXC;

  void* args[] = {(void*)&x,    (void*)&W1,     (void*)&Wsa1, (void*)&Wsa2,
                  (void*)&wt_w, (void*)&wsat_w, (void*)&wsat_b,
                  (void*)&bsa1, (void*)&pw1,    (void*)&pw2,  (void*)&pb1,
                  (void*)&pb2,  (void*)&lng,    (void*)&lnb,  (void*)&acc,
                  (void*)&Wt1,  (void*)&Wt2,    (void*)&out};
  hipLaunchCooperativeKernel((void*)mega, dim3(512), dim3(256), args, 0,
                             stream);
}

// Round 6
// 155.504 us; speedup vs baseline: 2.0312x; 2.0312x over previous
//
#include <hip/hip_runtime.h>

// CSATransformer: B=8, L=4096, DX=DQ=128, all f32.
// Math: (1) batch-constant softmax-logit term cancels in softmax -> dropped.
// (2) pairwise exp(sigmoid) separated via deg-6 Maclaurin + binomial moment
// sums: both O(L^2) passes -> O(L). Raw moments R_n = sum (e*t2)^n are
// accumulated BEFORE the softmax denominator is known, then rescaled by
// invS^n -> softmax + moment pass fuse. (3) FFN as bf16 MFMA.
// 4 wide launches; stream boundaries are the (cheap) global barriers.
// R5 lesson: cg::grid.sync() costs ~60us/sync here - never again.

#define SEQ 4096
#define NB 8
#define DXC 128
#define SQRTE 1.6487212707001282f
#define Y1S 136  // LDS row stride (bf16): 68 dwords -> 2-way banks (free)

typedef __attribute__((ext_vector_type(8))) short short8;
typedef __attribute__((ext_vector_type(4))) float f32x4;

__device__ __forceinline__ float wave_sum(float v) {
#pragma unroll
  for (int m = 32; m >= 1; m >>= 1) v += __shfl_xor(v, m);
  return v;
}

__device__ __forceinline__ float qwave_sum(float v) {
#pragma unroll
  for (int m = 8; m >= 1; m >>= 1) v += __shfl_xor(v, m);
  return v;
}

__device__ __forceinline__ unsigned short f2bf(float f) {
  unsigned int u = __float_as_uint(f);
  unsigned int r = (u + 0x7FFFu + ((u >> 16) & 1u)) >> 16;
  return (unsigned short)r;
}

__device__ __forceinline__ float dot128(const float* __restrict__ a,
                                        const float* __restrict__ b) {
  const float4* A = (const float4*)a;
  const float4* B = (const float4*)b;
  float s = 0.f;
#pragma unroll 8
  for (int i = 0; i < 32; ++i) {
    float4 u = A[i], v = B[i];
    s += u.x * v.x + u.y * v.y + u.z * v.z + u.w * v.w;
  }
  return s;
}

// Maclaurin coefficients of exp(sigmoid(t))/sqrt(e)
__device__ __forceinline__ void get_ck(float* ck) {
  ck[0] = 1.0f;
  ck[1] = 0.25f;
  ck[2] = 0.03125f;
  ck[3] = -7.0f / 384.0f;
  ck[4] = -31.0f / 6144.0f;
  ck[5] = 177.0f / 122880.0f;
  ck[6] = 2017.0f / 2949120.0f;
}

__device__ __forceinline__ float binomf(int k, int m) {
  const float B[7][7] = {
      {1, 0, 0, 0, 0, 0, 0},  {1, 1, 0, 0, 0, 0, 0},   {1, 2, 1, 0, 0, 0, 0},
      {1, 3, 3, 1, 0, 0, 0},  {1, 4, 6, 4, 1, 0, 0},   {1, 5, 10, 10, 5, 1, 0},
      {1, 6, 15, 20, 15, 6, 1}};
  return B[k][m];
}

// C_m = SQRTE * sum_n ck[m+n]*C(m+n,m)*V[n], m=0..6
__device__ __forceinline__ void sep_coeffs(const float* V, float* C) {
  float ck[7];
  get_ck(ck);
#pragma unroll
  for (int m = 0; m < 7; ++m) {
    float acc = 0.f;
    for (int n = 0; n <= 6 - m; ++n) acc += ck[m + n] * binomf(m + n, m) * V[n];
    C[m] = SQRTE * acc;
  }
}

__device__ __forceinline__ float horner7(const float* C, float a) {
  return (((((C[6] * a + C[5]) * a + C[4]) * a + C[3]) * a + C[2]) * a + C[1])
             * a + C[0];
}

__device__ __forceinline__ float g_exact(float t) {
  float sg = 1.0f / (1.0f + __expf(-t));
  return __expf(sg);
}

// ws layout (floats): [0..127] acc atomics ([0..7]=ssum/batch,
// [8+b*6+n]=R_{n+1}, [64+b*8+n]=T_n); [128..512] vecs v1/u1/u2 + ccst@512;
// arrays at 1024: ap, w, sj, dcol (32768 each); Wt1/Wt2 after.

// ---- K1: Wt pack (blocks 0..31), GEMVs (block 32), zero acc (block 33) ----
__global__ __launch_bounds__(256) void prep(
    const float* __restrict__ W1, const float* __restrict__ Wsa1,
    const float* __restrict__ Wsa2, const float* __restrict__ wt_w,
    const float* __restrict__ wsat_w, const float* __restrict__ wsat_b,
    const float* __restrict__ bsa1, const float* __restrict__ pw1,
    const float* __restrict__ pw2, float* __restrict__ ws_f,
    unsigned short* __restrict__ Wt1, unsigned short* __restrict__ Wt2) {
  int blk = blockIdx.x, tid = threadIdx.x;
  if (blk < 32) {
    int e0 = blk * 1024 + tid * 4;   // 4 consecutive output elems
    int which = e0 >> 14;            // 0: pw1, 1: pw2
    int k = e0 & 16383;
    int eo = k >> 7, d0 = k & 127;
    const float* pw = which ? pw2 : pw1;
    unsigned short* Wt = which ? Wt2 : Wt1;
#pragma unroll
    for (int j = 0; j < 4; ++j)
      Wt[eo * DXC + d0 + j] = f2bf(pw[(d0 + j) * DXC + eo]);
  } else if (blk == 32) {
    if (tid < 128) {
      ws_f[128 + tid] = dot128(W1 + tid * DXC, wt_w);
      ws_f[256 + tid] = dot128(Wsa1 + tid * DXC, wsat_w);
      ws_f[384 + tid] = dot128(Wsa2 + tid * DXC, wsat_w);
    } else if (tid == 128) {
      ws_f[512] = dot128(bsa1, wsat_w) + wsat_b[0];
    }
  } else {
    if (tid < 128) ws_f[tid] = 0.f;
  }
}

// ---- K2: rowdots + raw moments. 512 blocks x 256, 64 rows/block ----
__global__ __launch_bounds__(256) void rowstats(
    const float* __restrict__ x, const float* __restrict__ ws_f,
    float* __restrict__ ap_g, float* __restrict__ w_g,
    float* __restrict__ acc) {
  __shared__ float vs[3 * DXC];
  __shared__ float t0s[64], t1s[64], t2s[64];
  int tid = threadIdx.x, blk = blockIdx.x;
  int base = blk * 64;
  int b = blk >> 6;
  for (int k = tid; k < 384; k += 256) vs[k] = ws_f[128 + k];
  __syncthreads();
  int lane = tid & 63, wave = tid >> 6;
  int seg = lane & 15, sub = lane >> 4;
  float4 v00 = *(const float4*)&vs[0 * DXC + seg * 8];
  float4 v01 = *(const float4*)&vs[0 * DXC + seg * 8 + 4];
  float4 v10 = *(const float4*)&vs[1 * DXC + seg * 8];
  float4 v11 = *(const float4*)&vs[1 * DXC + seg * 8 + 4];
  float4 v20 = *(const float4*)&vs[2 * DXC + seg * 8];
  float4 v21 = *(const float4*)&vs[2 * DXC + seg * 8 + 4];
  const float* xb = x + (size_t)base * DXC;
#pragma unroll
  for (int p = 0; p < 4; ++p) {
    int rl = wave * 16 + p * 4 + sub;
    const float4* xp = (const float4*)(xb + (size_t)rl * DXC + seg * 8);
    float4 lo = xp[0], hi = xp[1];
    float s0 = lo.x * v00.x + lo.y * v00.y + lo.z * v00.z + lo.w * v00.w
             + hi.x * v01.x + hi.y * v01.y + hi.z * v01.z + hi.w * v01.w;
    float s1 = lo.x * v10.x + lo.y * v10.y + lo.z * v10.z + lo.w * v10.w
             + hi.x * v11.x + hi.y * v11.y + hi.z * v11.z + hi.w * v11.w;
    float s2 = lo.x * v20.x + lo.y * v20.y + lo.z * v20.z + lo.w * v20.w
             + hi.x * v21.x + hi.y * v21.y + hi.z * v21.z + hi.w * v21.w;
    s0 = qwave_sum(s0);
    s1 = qwave_sum(s1);
    s2 = qwave_sum(s2);
    if (seg == 0) { t0s[rl] = s0; t1s[rl] = s1; t2s[rl] = s2; }
  }
  __syncthreads();
  if (tid < 64) {
    float e = __expf(t0s[tid]);  // logits ~N(0,1): f32-safe without max-sub
    float w = e * t2s[tid];
    ap_g[base + tid] = e * t1s[tid];
    w_g[base + tid] = w;
    float r[7];
    r[0] = e;
    r[1] = w;
#pragma unroll
    for (int n = 2; n < 7; ++n) r[n] = r[n - 1] * w;
#pragma unroll
    for (int n = 0; n < 7; ++n) r[n] = wave_sum(r[n]);
    if (tid == 0) {
      atomicAdd(&acc[b], r[0]);
#pragma unroll
      for (int n = 1; n < 7; ++n) atomicAdd(&acc[8 + b * 6 + n - 1], r[n]);
    }
  }
}

// ---- K3: per-row Z, dcol, sj + T moments. 128 blocks x 256, 1 row/thread --
__global__ __launch_bounds__(256) void zqpass(
    const float* __restrict__ ap_g, const float* __restrict__ w_g,
    const float* __restrict__ ws_f, float* __restrict__ sj_g,
    float* __restrict__ dcol_g, float* __restrict__ acc) {
  __shared__ float red[4][7];
  int tid = threadIdx.x, blk = blockIdx.x;
  int gid = blk * 256 + tid;
  int b = blk >> 4;  // 16 blocks per batch
  float invS = 1.0f / acc[b];
  float Sv[7], P[7];
  Sv[0] = (float)SEQ;
  float ip = invS;
#pragma unroll
  for (int n = 1; n < 7; ++n) { Sv[n] = acc[8 + b * 6 + n - 1] * ip; ip *= invS; }
  sep_coeffs(Sv, P);
  float ccst = ws_f[512];
  float a = ap_g[gid] * invS + ccst;
  float bb = w_g[gid] * invS;
  float zf = horner7(P, a);
  float d = g_exact(a + bb);
  float iz = 1.0f / (zf - d);
  sj_g[gid] = bb;
  dcol_g[gid] = d * iz;
  float t[7];
  t[0] = iz;
#pragma unroll
  for (int n = 1; n < 7; ++n) t[n] = t[n - 1] * a;
#pragma unroll
  for (int n = 0; n < 7; ++n) t[n] = wave_sum(t[n]);
  int lane = tid & 63, wave = tid >> 6;
  if (lane == 0) {
#pragma unroll
    for (int n = 0; n < 7; ++n) red[wave][n] = t[n];
  }
  __syncthreads();
  if (tid < 7) {
    float s = red[0][tid] + red[1][tid] + red[2][tid] + red[3][tid];
    atomicAdd(&acc[64 + b * 8 + tid], s);
  }
}

// ---- K4: colsum + FFN (bf16 MFMA) + f32 residual + LayerNorm.
//      512 blocks x 256; 64 rows/block; wave owns a 16-row m-tile ----
__global__ __launch_bounds__(256) void ffn_mfma(
    const float* __restrict__ x, const float* __restrict__ sj_g,
    const float* __restrict__ dcol_g, const float* __restrict__ acc,
    const unsigned short* __restrict__ Wt1,
    const unsigned short* __restrict__ Wt2,
    const float* __restrict__ b1, const float* __restrict__ b2,
    const float* __restrict__ lng, const float* __restrict__ lnb,
    float* __restrict__ out) {
  __shared__ float cs[64];
  __shared__ __align__(16) unsigned short y1[64 * Y1S];  // 17.4 KB
  int tid = threadIdx.x;
  int base = blockIdx.x * 64;
  int b = blockIdx.x >> 6;
  if (tid < 64) {
    float Tv[7], Q[7];
#pragma unroll
    for (int n = 0; n < 7; ++n) Tv[n] = acc[64 + b * 8 + n];
    sep_coeffs(Tv, Q);
    int row = base + tid;
    cs[tid] = horner7(Q, sj_g[row]) - dcol_g[row];
  }
  __syncthreads();
  int lane = tid & 63, wave = tid >> 6;
  int n16 = lane & 15, quad = lane >> 4;
  int m0 = wave * 16;
  int rowA = base + m0 + n16;
  float csA = cs[m0 + n16];
  const float4* xr = (const float4*)(x + (size_t)rowA * DXC);
  short8 afr[4];
#pragma unroll
  for (int cc = 0; cc < 4; ++cc) {
    float4 p0 = xr[cc * 8 + quad * 2];
    float4 p1 = xr[cc * 8 + quad * 2 + 1];
    short8 af;
    af[0] = (short)f2bf(p0.x * csA); af[1] = (short)f2bf(p0.y * csA);
    af[2] = (short)f2bf(p0.z * csA); af[3] = (short)f2bf(p0.w * csA);
    af[4] = (short)f2bf(p1.x * csA); af[5] = (short)f2bf(p1.y * csA);
    af[6] = (short)f2bf(p1.z * csA); af[7] = (short)f2bf(p1.w * csA);
    afr[cc] = af;
  }
  // GEMM1: y1 = relu(ui @ W1p + b1) -> LDS row-major bf16
#pragma unroll
  for (int nt = 0; nt < 8; ++nt) {
    const unsigned short* wrow = Wt1 + (nt * 16 + n16) * DXC;
    f32x4 a = {0.f, 0.f, 0.f, 0.f};
#pragma unroll
    for (int cc = 0; cc < 4; ++cc) {
      short8 bf = *(const short8*)(wrow + cc * 32 + quad * 8);
      a = __builtin_amdgcn_mfma_f32_16x16x32_bf16(afr[cc], bf, a, 0, 0, 0);
    }
    float b1v = b1[nt * 16 + n16];
#pragma unroll
    for (int r = 0; r < 4; ++r) {
      float yv = fmaxf(a[r] + b1v, 0.f);
      y1[(m0 + quad * 4 + r) * Y1S + nt * 16 + n16] = f2bf(yv);
    }
  }
  __syncthreads();
  const unsigned short* yrow = &y1[(m0 + n16) * Y1S];
  short8 afr2[4];
#pragma unroll
  for (int cc = 0; cc < 4; ++cc)
    afr2[cc] = *(const short8*)(yrow + cc * 32 + quad * 8);
  f32x4 acc2[8];
#pragma unroll
  for (int nt = 0; nt < 8; ++nt) {
    const unsigned short* wrow = Wt2 + (nt * 16 + n16) * DXC;
    f32x4 a = {0.f, 0.f, 0.f, 0.f};
#pragma unroll
    for (int cc = 0; cc < 4; ++cc) {
      short8 bf = *(const short8*)(wrow + cc * 32 + quad * 8);
      a = __builtin_amdgcn_mfma_f32_16x16x32_bf16(afr2[cc], bf, a, 0, 0, 0);
    }
    acc2[nt] = a;
  }
  float b2v[8], lgv[8], lbv[8];
#pragma unroll
  for (int nt = 0; nt < 8; ++nt) {
    int col = nt * 16 + n16;
    b2v[nt] = b2[col]; lgv[nt] = lng[col]; lbv[nt] = lnb[col];
  }
#pragma unroll
  for (int r = 0; r < 4; ++r) {
    int rl = m0 + quad * 4 + r;
    int row = base + rl;
    float csr = cs[rl];
    const float* xrow = x + (size_t)row * DXC;
    float z[8];
    float s = 0.f, sq = 0.f;
#pragma unroll
    for (int nt = 0; nt < 8; ++nt) {
      int col = nt * 16 + n16;
      float zz = acc2[nt][r] + b2v[nt] + xrow[col] * csr;
      z[nt] = zz; s += zz; sq += zz * zz;
    }
#pragma unroll
    for (int mm = 8; mm >= 1; mm >>= 1) {
      s += __shfl_xor(s, mm);
      sq += __shfl_xor(sq, mm);
    }
    float mu = s * 0.0078125f;
    float var = sq * 0.0078125f - mu * mu;
    float rstd = 1.0f / sqrtf(var + 1e-6f);
    float* orow = out + (size_t)row * DXC;
#pragma unroll
    for (int nt = 0; nt < 8; ++nt) {
      int col = nt * 16 + n16;
      orow[col] = (z[nt] - mu) * rstd * lgv[nt] + lbv[nt];
    }
  }
}

extern "C" void kernel_launch(void* const* d_in, const int* in_sizes, int n_in,
                              void* d_out, int out_size, void* d_ws, size_t ws_size,
                              hipStream_t stream) {
  const float* x = (const float*)d_in[0];
  const float* W1 = (const float*)d_in[2];
  const float* wt_w = (const float*)d_in[4];
  const float* Wsa1 = (const float*)d_in[6];
  const float* Wsa2 = (const float*)d_in[7];
  const float* wsat_w = (const float*)d_in[8];
  const float* wsat_b = (const float*)d_in[9];
  const float* bsa1 = (const float*)d_in[10];
  const float* pw1 = (const float*)d_in[11];
  const float* pb1 = (const float*)d_in[12];
  const float* pw2 = (const float*)d_in[13];
  const float* pb2 = (const float*)d_in[14];
  const float* lng = (const float*)d_in[15];
  const float* lnb = (const float*)d_in[16];
  float* out = (float*)d_out;
  float* ws = (float*)d_ws;

  const int NR = NB * SEQ;  // 32768
  float* acc = ws;                    // 128
  float* ap_g = ws + 1024;            // 32768
  float* w_g = ap_g + NR;             // 32768
  float* sj_g = w_g + NR;             // 32768
  float* dcol_g = sj_g + NR;          // 32768
  unsigned short* Wt1 = (unsigned short*)(dcol_g + NR);
  unsigned short* Wt2 = Wt1 + DXC * DXC;

  prep<<<34, 256, 0, stream>>>(W1, Wsa1, Wsa2, wt_w, wsat_w, wsat_b, bsa1,
                               pw1, pw2, ws, Wt1, Wt2);
  rowstats<<<512, 256, 0, stream>>>(x, ws, ap_g, w_g, acc);
  zqpass<<<128, 256, 0, stream>>>(ap_g, w_g, ws, sj_g, dcol_g, acc);
  ffn_mfma<<<512, 256, 0, stream>>>(x, sj_g, dcol_g, acc, Wt1, Wt2, pb1, pb2,
                                    lng, lnb, out);
}

// Round 7
// 133.720 us; speedup vs baseline: 2.3621x; 1.1629x over previous
//
#include <hip/hip_runtime.h>

// CSATransformer: B=8, L=4096, DX=DQ=128, all f32.
// Math: (1) batch-constant softmax-logit term cancels in softmax -> dropped.
// (2) pairwise exp(sigmoid) separated via deg-6 Maclaurin + binomial moment
// sums: both O(L^2) passes -> O(L). Raw moments R_n = sum (e*t2)^n are
// accumulated BEFORE the softmax denominator is known, then rescaled by
// invS^n. (3) FFN as bf16 MFMA. (4) NO atomics: block-partial moment trees
// (part1: 512x8, part2: 128x8) -> no zero-init -> no prep launch.
// 3 wide launches = the dataflow-minimum global barriers.
// R5 lesson: cg::grid.sync() costs ~60us/sync here; stream boundaries ~2us.

#define SEQ 4096
#define NB 8
#define DXC 128
#define SQRTE 1.6487212707001282f
#define Y1S 136  // LDS row stride (bf16): 68 dwords -> 2-way banks (free)

typedef __attribute__((ext_vector_type(8))) short short8;
typedef __attribute__((ext_vector_type(4))) float f32x4;

__device__ __forceinline__ float wave_sum(float v) {
#pragma unroll
  for (int m = 32; m >= 1; m >>= 1) v += __shfl_xor(v, m);
  return v;
}

__device__ __forceinline__ float qwave_sum(float v) {
#pragma unroll
  for (int m = 8; m >= 1; m >>= 1) v += __shfl_xor(v, m);
  return v;
}

__device__ __forceinline__ unsigned short f2bf(float f) {
  unsigned int u = __float_as_uint(f);
  unsigned int r = (u + 0x7FFFu + ((u >> 16) & 1u)) >> 16;
  return (unsigned short)r;
}

__device__ __forceinline__ float dot128(const float* __restrict__ a,
                                        const float* __restrict__ b) {
  const float4* A = (const float4*)a;
  const float4* B = (const float4*)b;
  float s = 0.f;
#pragma unroll 8
  for (int i = 0; i < 32; ++i) {
    float4 u = A[i], v = B[i];
    s += u.x * v.x + u.y * v.y + u.z * v.z + u.w * v.w;
  }
  return s;
}

// Maclaurin coefficients of exp(sigmoid(t))/sqrt(e)
__device__ __forceinline__ void get_ck(float* ck) {
  ck[0] = 1.0f;
  ck[1] = 0.25f;
  ck[2] = 0.03125f;
  ck[3] = -7.0f / 384.0f;
  ck[4] = -31.0f / 6144.0f;
  ck[5] = 177.0f / 122880.0f;
  ck[6] = 2017.0f / 2949120.0f;
}

__device__ __forceinline__ float binomf(int k, int m) {
  const float B[7][7] = {
      {1, 0, 0, 0, 0, 0, 0},  {1, 1, 0, 0, 0, 0, 0},   {1, 2, 1, 0, 0, 0, 0},
      {1, 3, 3, 1, 0, 0, 0},  {1, 4, 6, 4, 1, 0, 0},   {1, 5, 10, 10, 5, 1, 0},
      {1, 6, 15, 20, 15, 6, 1}};
  return B[k][m];
}

// C_m = SQRTE * sum_n ck[m+n]*C(m+n,m)*V[n], m=0..6
__device__ __forceinline__ void sep_coeffs(const float* V, float* C) {
  float ck[7];
  get_ck(ck);
#pragma unroll
  for (int m = 0; m < 7; ++m) {
    float acc = 0.f;
    for (int n = 0; n <= 6 - m; ++n) acc += ck[m + n] * binomf(m + n, m) * V[n];
    C[m] = SQRTE * acc;
  }
}

__device__ __forceinline__ float horner7(const float* C, float a) {
  return (((((C[6] * a + C[5]) * a + C[4]) * a + C[3]) * a + C[2]) * a + C[1])
             * a + C[0];
}

__device__ __forceinline__ float g_exact(float t) {
  float sg = 1.0f / (1.0f + __expf(-t));
  return __expf(sg);
}

// ---- K1: GEMVs (per-block, L2-hot) + rowdots + block moment partials.
//      512 blocks x 256, 64 rows/block ----
__global__ __launch_bounds__(256) void rowstats(
    const float* __restrict__ x, const float* __restrict__ W1,
    const float* __restrict__ Wsa1, const float* __restrict__ Wsa2,
    const float* __restrict__ wt_w, const float* __restrict__ wsat_w,
    float* __restrict__ ap_g, float* __restrict__ w_g,
    float* __restrict__ part1) {
  __shared__ float vs[3 * DXC];
  __shared__ float t0s[64], t1s[64], t2s[64];
  int tid = threadIdx.x, blk = blockIdx.x;
  int base = blk * 64;
  // redundant per-block GEMVs (weights are L2-resident)
  if (tid < 128) {
    vs[tid] = dot128(W1 + tid * DXC, wt_w);
    vs[2 * DXC + tid] = dot128(Wsa2 + tid * DXC, wsat_w);
  } else {
    int d = tid - 128;
    vs[DXC + d] = dot128(Wsa1 + d * DXC, wsat_w);
  }
  __syncthreads();
  int lane = tid & 63, wave = tid >> 6;
  int seg = lane & 15, sub = lane >> 4;
  float4 v00 = *(const float4*)&vs[0 * DXC + seg * 8];
  float4 v01 = *(const float4*)&vs[0 * DXC + seg * 8 + 4];
  float4 v10 = *(const float4*)&vs[1 * DXC + seg * 8];
  float4 v11 = *(const float4*)&vs[1 * DXC + seg * 8 + 4];
  float4 v20 = *(const float4*)&vs[2 * DXC + seg * 8];
  float4 v21 = *(const float4*)&vs[2 * DXC + seg * 8 + 4];
  const float* xb = x + (size_t)base * DXC;
#pragma unroll
  for (int p = 0; p < 4; ++p) {
    int rl = wave * 16 + p * 4 + sub;
    const float4* xp = (const float4*)(xb + (size_t)rl * DXC + seg * 8);
    float4 lo = xp[0], hi = xp[1];
    float s0 = lo.x * v00.x + lo.y * v00.y + lo.z * v00.z + lo.w * v00.w
             + hi.x * v01.x + hi.y * v01.y + hi.z * v01.z + hi.w * v01.w;
    float s1 = lo.x * v10.x + lo.y * v10.y + lo.z * v10.z + lo.w * v10.w
             + hi.x * v11.x + hi.y * v11.y + hi.z * v11.z + hi.w * v11.w;
    float s2 = lo.x * v20.x + lo.y * v20.y + lo.z * v20.z + lo.w * v20.w
             + hi.x * v21.x + hi.y * v21.y + hi.z * v21.z + hi.w * v21.w;
    s0 = qwave_sum(s0);
    s1 = qwave_sum(s1);
    s2 = qwave_sum(s2);
    if (seg == 0) { t0s[rl] = s0; t1s[rl] = s1; t2s[rl] = s2; }
  }
  __syncthreads();
  if (tid < 64) {
    float e = __expf(t0s[tid]);  // logits ~N(0,1): f32-safe without max-sub
    float w = e * t2s[tid];
    ap_g[base + tid] = e * t1s[tid];
    w_g[base + tid] = w;
    float r[7];
    r[0] = e;
    r[1] = w;
#pragma unroll
    for (int n = 2; n < 7; ++n) r[n] = r[n - 1] * w;
#pragma unroll
    for (int n = 0; n < 7; ++n) r[n] = wave_sum(r[n]);
    if (tid == 0) {
#pragma unroll
      for (int n = 0; n < 7; ++n) part1[blk * 8 + n] = r[n];
    }
  }
}

// ---- K2: S totals -> P; per-row Z, dcol, sj; T block partials; Wt pack.
//      128 blocks x 256, 1 row/thread ----
__global__ __launch_bounds__(256) void zqpass(
    const float* __restrict__ ap_g, const float* __restrict__ w_g,
    const float* __restrict__ part1, const float* __restrict__ bsa1,
    const float* __restrict__ wsat_w, const float* __restrict__ wsat_b,
    const float* __restrict__ pw1, const float* __restrict__ pw2,
    float* __restrict__ sj_g, float* __restrict__ dcol_g,
    float* __restrict__ part2, unsigned short* __restrict__ Wt1,
    unsigned short* __restrict__ Wt2) {
  __shared__ float Ss[8];
  __shared__ float ccst_sh;
  __shared__ float red[4][7];
  int tid = threadIdx.x, blk = blockIdx.x;
  int gid = blk * 256 + tid;
  int b = blk >> 4;  // 16 blocks per batch
  // Wt bf16 transpose-pack: exactly one element per thread grid-wide
  {
    int which = gid >> 14;  // 0: pw1, 1: pw2
    int k = gid & 16383;
    int eo = k >> 7, dd = k & 127;
    const float* pw = which ? pw2 : pw1;
    unsigned short* Wt = which ? Wt2 : Wt1;
    Wt[eo * DXC + dd] = f2bf(pw[dd * DXC + eo]);
  }
  // wave 0: reduce part1 over this batch's 64 rowstats blocks
  if (tid < 64) {
    const float* p = part1 + ((size_t)b * 64 + tid) * 8;
    float r[7];
#pragma unroll
    for (int n = 0; n < 7; ++n) r[n] = p[n];
#pragma unroll
    for (int n = 0; n < 7; ++n) r[n] = wave_sum(r[n]);
    if (tid == 0) {
#pragma unroll
      for (int n = 0; n < 7; ++n) Ss[n] = r[n];
    }
  }
  // wave 1: ccst = bsa1.wsat_w + wsat_b
  if (tid >= 64 && tid < 128) {
    int l = tid - 64;
    float2 bv = ((const float2*)bsa1)[l];
    float2 wv = ((const float2*)wsat_w)[l];
    float s = wave_sum(bv.x * wv.x + bv.y * wv.y);
    if (l == 0) ccst_sh = s + wsat_b[0];
  }
  __syncthreads();
  float invS = 1.0f / Ss[0];
  float Sv[7], P[7];
  Sv[0] = (float)SEQ;
  float ip = invS;
#pragma unroll
  for (int n = 1; n < 7; ++n) { Sv[n] = Ss[n] * ip; ip *= invS; }
  sep_coeffs(Sv, P);
  float a = ap_g[gid] * invS + ccst_sh;
  float bb = w_g[gid] * invS;
  float zf = horner7(P, a);
  float d = g_exact(a + bb);
  float iz = 1.0f / (zf - d);
  sj_g[gid] = bb;
  dcol_g[gid] = d * iz;
  float t[7];
  t[0] = iz;
#pragma unroll
  for (int n = 1; n < 7; ++n) t[n] = t[n - 1] * a;
#pragma unroll
  for (int n = 0; n < 7; ++n) t[n] = wave_sum(t[n]);
  int lane = tid & 63, wave = tid >> 6;
  if (lane == 0) {
#pragma unroll
    for (int n = 0; n < 7; ++n) red[wave][n] = t[n];
  }
  __syncthreads();
  if (tid < 7) {
    part2[blk * 8 + tid] =
        red[0][tid] + red[1][tid] + red[2][tid] + red[3][tid];
  }
}

// ---- K3: T totals -> Q; colsum; FFN (bf16 MFMA) + f32 residual + LN.
//      512 blocks x 256; 64 rows/block; wave owns a 16-row m-tile ----
__global__ __launch_bounds__(256) void ffn_mfma(
    const float* __restrict__ x, const float* __restrict__ sj_g,
    const float* __restrict__ dcol_g, const float* __restrict__ part2,
    const unsigned short* __restrict__ Wt1,
    const unsigned short* __restrict__ Wt2,
    const float* __restrict__ b1, const float* __restrict__ b2,
    const float* __restrict__ lng, const float* __restrict__ lnb,
    float* __restrict__ out) {
  __shared__ float Ts[8];
  __shared__ float cs[64];
  __shared__ __align__(16) unsigned short y1[64 * Y1S];  // 17.4 KB
  int tid = threadIdx.x;
  int base = blockIdx.x * 64;
  int b = blockIdx.x >> 6;
  if (tid < 7) {
    float s = 0.f;
#pragma unroll
    for (int j = 0; j < 16; ++j) s += part2[((size_t)b * 16 + j) * 8 + tid];
    Ts[tid] = s;
  }
  __syncthreads();
  if (tid < 64) {
    float Tv[7], Q[7];
#pragma unroll
    for (int n = 0; n < 7; ++n) Tv[n] = Ts[n];
    sep_coeffs(Tv, Q);
    int row = base + tid;
    cs[tid] = horner7(Q, sj_g[row]) - dcol_g[row];
  }
  __syncthreads();
  int lane = tid & 63, wave = tid >> 6;
  int n16 = lane & 15, quad = lane >> 4;
  int m0 = wave * 16;
  int rowA = base + m0 + n16;
  float csA = cs[m0 + n16];
  const float4* xr = (const float4*)(x + (size_t)rowA * DXC);
  short8 afr[4];
#pragma unroll
  for (int cc = 0; cc < 4; ++cc) {
    float4 p0 = xr[cc * 8 + quad * 2];
    float4 p1 = xr[cc * 8 + quad * 2 + 1];
    short8 af;
    af[0] = (short)f2bf(p0.x * csA); af[1] = (short)f2bf(p0.y * csA);
    af[2] = (short)f2bf(p0.z * csA); af[3] = (short)f2bf(p0.w * csA);
    af[4] = (short)f2bf(p1.x * csA); af[5] = (short)f2bf(p1.y * csA);
    af[6] = (short)f2bf(p1.z * csA); af[7] = (short)f2bf(p1.w * csA);
    afr[cc] = af;
  }
  // GEMM1: y1 = relu(ui @ W1p + b1) -> LDS row-major bf16
#pragma unroll
  for (int nt = 0; nt < 8; ++nt) {
    const unsigned short* wrow = Wt1 + (nt * 16 + n16) * DXC;
    f32x4 a = {0.f, 0.f, 0.f, 0.f};
#pragma unroll
    for (int cc = 0; cc < 4; ++cc) {
      short8 bf = *(const short8*)(wrow + cc * 32 + quad * 8);
      a = __builtin_amdgcn_mfma_f32_16x16x32_bf16(afr[cc], bf, a, 0, 0, 0);
    }
    float b1v = b1[nt * 16 + n16];
#pragma unroll
    for (int r = 0; r < 4; ++r) {
      float yv = fmaxf(a[r] + b1v, 0.f);
      y1[(m0 + quad * 4 + r) * Y1S + nt * 16 + n16] = f2bf(yv);
    }
  }
  __syncthreads();
  const unsigned short* yrow = &y1[(m0 + n16) * Y1S];
  short8 afr2[4];
#pragma unroll
  for (int cc = 0; cc < 4; ++cc)
    afr2[cc] = *(const short8*)(yrow + cc * 32 + quad * 8);
  f32x4 acc2[8];
#pragma unroll
  for (int nt = 0; nt < 8; ++nt) {
    const unsigned short* wrow = Wt2 + (nt * 16 + n16) * DXC;
    f32x4 a = {0.f, 0.f, 0.f, 0.f};
#pragma unroll
    for (int cc = 0; cc < 4; ++cc) {
      short8 bf = *(const short8*)(wrow + cc * 32 + quad * 8);
      a = __builtin_amdgcn_mfma_f32_16x16x32_bf16(afr2[cc], bf, a, 0, 0, 0);
    }
    acc2[nt] = a;
  }
  float b2v[8], lgv[8], lbv[8];
#pragma unroll
  for (int nt = 0; nt < 8; ++nt) {
    int col = nt * 16 + n16;
    b2v[nt] = b2[col]; lgv[nt] = lng[col]; lbv[nt] = lnb[col];
  }
#pragma unroll
  for (int r = 0; r < 4; ++r) {
    int rl = m0 + quad * 4 + r;
    int row = base + rl;
    float csr = cs[rl];
    const float* xrow = x + (size_t)row * DXC;
    float z[8];
    float s = 0.f, sq = 0.f;
#pragma unroll
    for (int nt = 0; nt < 8; ++nt) {
      int col = nt * 16 + n16;
      float zz = acc2[nt][r] + b2v[nt] + xrow[col] * csr;
      z[nt] = zz; s += zz; sq += zz * zz;
    }
#pragma unroll
    for (int mm = 8; mm >= 1; mm >>= 1) {
      s += __shfl_xor(s, mm);
      sq += __shfl_xor(sq, mm);
    }
    float mu = s * 0.0078125f;
    float var = sq * 0.0078125f - mu * mu;
    float rstd = 1.0f / sqrtf(var + 1e-6f);
    float* orow = out + (size_t)row * DXC;
#pragma unroll
    for (int nt = 0; nt < 8; ++nt) {
      int col = nt * 16 + n16;
      orow[col] = (z[nt] - mu) * rstd * lgv[nt] + lbv[nt];
    }
  }
}

extern "C" void kernel_launch(void* const* d_in, const int* in_sizes, int n_in,
                              void* d_out, int out_size, void* d_ws, size_t ws_size,
                              hipStream_t stream) {
  const float* x = (const float*)d_in[0];
  const float* W1 = (const float*)d_in[2];
  const float* wt_w = (const float*)d_in[4];
  const float* Wsa1 = (const float*)d_in[6];
  const float* Wsa2 = (const float*)d_in[7];
  const float* wsat_w = (const float*)d_in[8];
  const float* wsat_b = (const float*)d_in[9];
  const float* bsa1 = (const float*)d_in[10];
  const float* pw1 = (const float*)d_in[11];
  const float* pb1 = (const float*)d_in[12];
  const float* pw2 = (const float*)d_in[13];
  const float* pb2 = (const float*)d_in[14];
  const float* lng = (const float*)d_in[15];
  const float* lnb = (const float*)d_in[16];
  float* out = (float*)d_out;
  float* ws = (float*)d_ws;

  const int NR = NB * SEQ;  // 32768
  float* part1 = ws;                   // 512*8 = 4096
  float* part2 = ws + 4096;            // 128*8 = 1024
  float* ap_g = ws + 8192;             // 32768
  float* w_g = ap_g + NR;              // 32768
  float* sj_g = w_g + NR;              // 32768
  float* dcol_g = sj_g + NR;           // 32768
  unsigned short* Wt1 = (unsigned short*)(dcol_g + NR);  // 16384 ushort
  unsigned short* Wt2 = Wt1 + DXC * DXC;

  rowstats<<<512, 256, 0, stream>>>(x, W1, Wsa1, Wsa2, wt_w, wsat_w, ap_g,
                                    w_g, part1);
  zqpass<<<128, 256, 0, stream>>>(ap_g, w_g, part1, bsa1, wsat_w, wsat_b,
                                  pw1, pw2, sj_g, dcol_g, part2, Wt1, Wt2);
  ffn_mfma<<<512, 256, 0, stream>>>(x, sj_g, dcol_g, part2, Wt1, Wt2, pb1,
                                    pb2, lng, lnb, out);
}